// Round 5
// baseline (317.930 us; speedup 1.0000x reference)
//
#include <hip/hip_runtime.h>

// ============================================================================
// LeViT attention, MI355X. I/O tensors are FLOAT32 (per reference).
// b=2, C=256, H=W=56, n=3136, heads=8, kd=16, dh=64.
// ws layout (u16 bf16 elems): q[2*8*3136*16] | k[same] | v[2*512*3136] | o[same]
//   q,k: [bh][n][16]  (token-major -> 16B MFMA A/B frag loads)
//   v,o: [b][ch][n]   (channel-major -> 16B PV B-frag loads / proj GEMM reads)
// MFMA 16x16x32_bf16 layouts (HW-verified per guide):
//   A[m=lane&15][k=(lane>>4)*8+j]; B[k=(lane>>4)*8+j][n=lane&15]
//   C/D: col=lane&15, row=(lane>>4)*4+reg
// Round-5 attn: 64-key chunks (49 chunks, wave w takes c%4==w -> <=13 iters),
// P staged in LDS as bf16 (A-frags = raw ds_read_b128, no post-cvt), K-frag
// register prefetch 1 chunk ahead, V issued early (hides under exp/LDS),
// pbuf/obuf union (20.7KB LDS), additive partial-O merge (no-max softmax).
// ============================================================================

typedef short  s16x8 __attribute__((ext_vector_type(8)));
typedef float  f32x4 __attribute__((ext_vector_type(4)));
typedef unsigned short u16;
typedef unsigned short u16x4 __attribute__((ext_vector_type(4)));

__device__ __forceinline__ float bf2f(u16 v) {
    unsigned u = ((unsigned)v) << 16;
    return __builtin_bit_cast(float, u);
}
__device__ __forceinline__ u16 f2bf(float f) {   // RNE
    unsigned u = __builtin_bit_cast(unsigned, f);
    u += 0x7FFF + ((u >> 16) & 1);
    return (u16)(u >> 16);
}

// ---------------------------------------------------------------------------
// Kernel 1: QKV projection (fp32 in, bf16 ws out).  [unchanged]
// ---------------------------------------------------------------------------
__global__ __launch_bounds__(256) void qkv_kernel(
    const float* __restrict__ x,
    const float* __restrict__ wq, const float* __restrict__ sq, const float* __restrict__ bq,
    const float* __restrict__ wk, const float* __restrict__ sk, const float* __restrict__ bk,
    const float* __restrict__ wv, const float* __restrict__ sv, const float* __restrict__ bv,
    u16* __restrict__ qws, u16* __restrict__ kws, u16* __restrict__ vws)
{
    const int b  = blockIdx.z;
    const int rt = blockIdx.y;
    const int n0 = blockIdx.x * 64;

    const float *W, *Sc, *Bi; int row0, kind;
    if (rt < 2)      { W = wq; Sc = sq; Bi = bq; row0 = rt * 64;       kind = 0; }
    else if (rt < 4) { W = wk; Sc = sk; Bi = bk; row0 = (rt - 2) * 64; kind = 1; }
    else             { W = wv; Sc = sv; Bi = bv; row0 = (rt - 4) * 64; kind = 2; }

    __shared__ float As[16][64];
    __shared__ float Bs[16][64];

    const int t  = threadIdx.x;
    const int tm = t >> 4, tn = t & 15;
    const int am = t >> 2, ak = (t & 3) * 4;
    const int bn = t & 63, bk0 = (t >> 6) * 4;

    float acc[4][4];
    #pragma unroll
    for (int i = 0; i < 4; i++)
        #pragma unroll
        for (int j = 0; j < 4; j++) acc[i][j] = 0.f;

    for (int kc = 0; kc < 256; kc += 16) {
        f32x4 w4 = *(const f32x4*)&W[(row0 + am) * 256 + kc + ak];
        #pragma unroll
        for (int j = 0; j < 4; j++) As[ak + j][am] = w4[j];
        #pragma unroll
        for (int j = 0; j < 4; j++)
            Bs[bk0 + j][bn] = x[(b * 256 + kc + bk0 + j) * 3136 + n0 + bn];
        __syncthreads();
        #pragma unroll
        for (int kk = 0; kk < 16; kk++) {
            f32x4 a  = *(const f32x4*)&As[kk][tm * 4];
            f32x4 bb = *(const f32x4*)&Bs[kk][tn * 4];
            #pragma unroll
            for (int i = 0; i < 4; i++)
                #pragma unroll
                for (int j = 0; j < 4; j++) acc[i][j] = fmaf(a[i], bb[j], acc[i][j]);
        }
        __syncthreads();
    }

    #pragma unroll
    for (int i = 0; i < 4; i++) {
        const int ocl = row0 + tm * 4 + i;
        const float sc = Sc[ocl], bi = Bi[ocl];
        if (kind == 2) {
            u16x4 o4;
            #pragma unroll
            for (int j = 0; j < 4; j++) o4[j] = f2bf(acc[i][j] * sc + bi);
            *(u16x4*)&vws[(b * 512 + ocl) * 3136 + n0 + tn * 4] = o4;
        } else {
            u16* dst = (kind == 0) ? qws : kws;
            const int h = ocl >> 4, d = ocl & 15;
            #pragma unroll
            for (int j = 0; j < 4; j++) {
                const int n = n0 + tn * 4 + j;
                dst[((b * 8 + h) * 3136 + n) * 16 + d] = f2bf(acc[i][j] * sc + bi);
            }
        }
    }
}

// ---------------------------------------------------------------------------
// Kernel 2: flash attention v4. grid (16 bh, 196 q-tiles of 16); 4 waves.
// Wave w processes key-chunks c in {w, w+4, ...} (64 keys each, 49 total).
// ---------------------------------------------------------------------------
__global__ __launch_bounds__(256, 4) void attn_kernel(
    const u16* __restrict__ qws, const u16* __restrict__ kws,
    const u16* __restrict__ vws, u16* __restrict__ ows)
{
    const int bh   = blockIdx.x;                 // x fastest -> XCD = bh%8
    const int tile = blockIdx.y;
    const int t    = threadIdx.x;
    const int wave = t >> 6, lane = t & 63;
    const int l15  = lane & 15, quad = lane >> 4;
    const int kq   = quad & 1;                   // all lanes load valid K addrs
    const int nb   = tile * 16;                  // query base for this block

    // per-wave 5120B region: u16 pbuf[16][68] (2176B) during loop,
    // float obuf[64][20] (5120B) for the final merge.
    __shared__ __align__(16) unsigned char smem[4][5120];
    __shared__ float rbuf[4][16];
    u16* pw = (u16*)&smem[wave][0];

    // Q fragment: A[m=l15][k=quad*8+j]; kd=16 padded to K=32 with zeros
    s16x8 aq = {0, 0, 0, 0, 0, 0, 0, 0};
    if (quad < 2)
        aq = *(const s16x8*)&qws[(bh * 3136 + nb + l15) * 16 + quad * 8];

    float rsum[4] = {0.f, 0.f, 0.f, 0.f};
    f32x4 acc[4];                                 // 4 d-tiles x 4 rows
    #pragma unroll
    for (int dt = 0; dt < 4; dt++) acc[dt] = (f32x4){0.f, 0.f, 0.f, 0.f};

    const u16* kb = &kws[bh * 3136 * 16];
    const u16* vb = &vws[bh * 64 * 3136];        // (b*512+h*64) == bh*64
    const float L2E = 1.44269504088896f;

    // ---- preload K frags for first chunk (c = wave)
    s16x8 kf[4];
    #pragma unroll
    for (int i = 0; i < 4; i++)
        kf[i] = *(const s16x8*)&kb[(wave * 64 + i * 16 + l15) * 16 + kq * 8];

    for (int c = wave; c < 49; c += 4) {
        const int k0 = c * 64;
        // ---- S = Q*K^T : 4 key sub-tiles of 16
        const f32x4 z = {0.f, 0.f, 0.f, 0.f};
        f32x4 s[4];
        #pragma unroll
        for (int i = 0; i < 4; i++)
            s[i] = __builtin_amdgcn_mfma_f32_16x16x32_bf16(aq, kf[i], z, 0, 0, 0);

        // ---- prefetch next chunk's K (one chunk ahead)
        const int cn = (c + 4 < 49) ? (c + 4) : c;
        s16x8 kn[4];
        #pragma unroll
        for (int i = 0; i < 4; i++)
            kn[i] = *(const s16x8*)&kb[(cn * 64 + i * 16 + l15) * 16 + kq * 8];

        // ---- issue V for the CURRENT chunk early (latency hides under exp/LDS)
        s16x8 vf[2][4];
        #pragma unroll
        for (int g = 0; g < 2; g++)
            #pragma unroll
            for (int dt = 0; dt < 4; dt++)
                vf[g][dt] = *(const s16x8*)&vb[(dt * 16 + l15) * 3136 + k0 + g * 32 + quad * 8];

        // ---- P = exp2(S*log2e) -> bf16 straight into LDS (C-layout rows)
        #pragma unroll
        for (int i = 0; i < 4; i++) {
            #pragma unroll
            for (int r = 0; r < 4; r++) {
                const float p = __builtin_amdgcn_exp2f(s[i][r] * L2E);
                rsum[r] += p;
                pw[(quad * 4 + r) * 68 + i * 16 + l15] = f2bf(p);
            }
        }
        __builtin_amdgcn_wave_barrier();   // in-order DS: writes precede reads

        // ---- A-frags for P: row=l15(query), k=key offset; raw bf16, no cvt
        s16x8 ap0 = *(const s16x8*)&pw[l15 * 68 + quad * 8];
        s16x8 ap1 = *(const s16x8*)&pw[l15 * 68 + 32 + quad * 8];
        __builtin_amdgcn_wave_barrier();   // reads precede next iter's writes

        // ---- O += P*V  (full K=32, 8 MFMAs)
        #pragma unroll
        for (int dt = 0; dt < 4; dt++) {
            acc[dt] = __builtin_amdgcn_mfma_f32_16x16x32_bf16(ap0, vf[0][dt], acc[dt], 0, 0, 0);
            acc[dt] = __builtin_amdgcn_mfma_f32_16x16x32_bf16(ap1, vf[1][dt], acc[dt], 0, 0, 0);
        }

        #pragma unroll
        for (int i = 0; i < 4; i++) kf[i] = kn[i];
    }

    // ---- in-wave rowsum reduction (16 key-lanes of each quad)
    #pragma unroll
    for (int r = 0; r < 4; r++) {
        #pragma unroll
        for (int off = 8; off >= 1; off >>= 1)
            rsum[r] += __shfl_xor(rsum[r], off, 64);
    }
    if (l15 == 0) {
        #pragma unroll
        for (int r = 0; r < 4; r++) rbuf[wave][quad * 4 + r] = rsum[r];
    }
    // ---- publish partial O into own region (own loop is done; repurpose pbuf)
    float* ob_own = (float*)&smem[wave][0];
    #pragma unroll
    for (int dt = 0; dt < 4; dt++)
        *(f32x4*)&ob_own[lane * 20 + dt * 4] = acc[dt];

    __syncthreads();

    // ---- additive merge; wave w owns d-tile dt=w
    f32x4 om = {0.f, 0.f, 0.f, 0.f};
    #pragma unroll
    for (int w = 0; w < 4; w++) {
        const float* obw = (const float*)&smem[w][0];
        f32x4 p = *(const f32x4*)&obw[lane * 20 + wave * 4];
        #pragma unroll
        for (int r = 0; r < 4; r++) om[r] += p[r];
    }
    float rtot[4];
    #pragma unroll
    for (int r = 0; r < 4; r++) {
        const int row = quad * 4 + r;
        rtot[r] = 1.0f / (rbuf[0][row] + rbuf[1][row] + rbuf[2][row] + rbuf[3][row]);
    }
    u16x4 o4;
    #pragma unroll
    for (int r = 0; r < 4; r++) o4[r] = f2bf(om[r] * rtot[r]);
    // C-layout: col=d_local, rows = 4 consecutive n -> packed 8B store
    *(u16x4*)&ows[(bh * 64 + wave * 16 + l15) * 3136 + nb + quad * 4] = o4;
}

// ---------------------------------------------------------------------------
// Kernel 3: output projection (bf16 ws in, fp32 out).  [unchanged]
// ---------------------------------------------------------------------------
__global__ __launch_bounds__(256) void proj_kernel(
    const u16* __restrict__ ows, const float* __restrict__ wp,
    const float* __restrict__ sp, const float* __restrict__ bp,
    float* __restrict__ out)
{
    const int b  = blockIdx.z;
    const int n0 = blockIdx.x * 64;
    const int row0 = blockIdx.y * 64;

    __shared__ float As[16][64];
    __shared__ float Bs[16][64];

    const int t  = threadIdx.x;
    const int tm = t >> 4, tn = t & 15;
    const int am = t >> 2, ak = (t & 3) * 4;
    const int bn = t & 63, bk0 = (t >> 6) * 4;

    float acc[4][4];
    #pragma unroll
    for (int i = 0; i < 4; i++)
        #pragma unroll
        for (int j = 0; j < 4; j++) acc[i][j] = 0.f;

    for (int kc = 0; kc < 512; kc += 16) {
        f32x4 w4 = *(const f32x4*)&wp[(row0 + am) * 512 + kc + ak];
        #pragma unroll
        for (int j = 0; j < 4; j++) As[ak + j][am] = w4[j];
        #pragma unroll
        for (int j = 0; j < 4; j++)
            Bs[bk0 + j][bn] = bf2f(ows[(b * 512 + kc + bk0 + j) * 3136 + n0 + bn]);
        __syncthreads();
        #pragma unroll
        for (int kk = 0; kk < 16; kk++) {
            f32x4 a  = *(const f32x4*)&As[kk][tm * 4];
            f32x4 bb = *(const f32x4*)&Bs[kk][tn * 4];
            #pragma unroll
            for (int i = 0; i < 4; i++)
                #pragma unroll
                for (int j = 0; j < 4; j++) acc[i][j] = fmaf(a[i], bb[j], acc[i][j]);
        }
        __syncthreads();
    }

    #pragma unroll
    for (int i = 0; i < 4; i++) {
        const int oc = row0 + tm * 4 + i;
        const float sc = sp[oc], bi = bp[oc];
        f32x4 o4;
        #pragma unroll
        for (int j = 0; j < 4; j++) o4[j] = acc[i][j] * sc + bi;
        *(f32x4*)&out[(b * 256 + oc) * 3136 + n0 + tn * 4] = o4;
    }
}

// ---------------------------------------------------------------------------
extern "C" void kernel_launch(void* const* d_in, const int* in_sizes, int n_in,
                              void* d_out, int out_size, void* d_ws, size_t ws_size,
                              hipStream_t stream) {
    const float* x  = (const float*)d_in[0];
    const float* wq = (const float*)d_in[1];
    const float* sq = (const float*)d_in[2];
    const float* bq = (const float*)d_in[3];
    const float* wk = (const float*)d_in[4];
    const float* sk = (const float*)d_in[5];
    const float* bk = (const float*)d_in[6];
    const float* wv = (const float*)d_in[7];
    const float* sv = (const float*)d_in[8];
    const float* bv = (const float*)d_in[9];
    const float* wp = (const float*)d_in[10];
    const float* sp = (const float*)d_in[11];
    const float* bp = (const float*)d_in[12];
    float* out = (float*)d_out;

    u16* qws = (u16*)d_ws;                       // 2*8*3136*16 = 802816
    u16* kws = qws + 2 * 8 * 3136 * 16;
    u16* vws = kws + 2 * 8 * 3136 * 16;          // 2*512*3136 = 3211264
    u16* ows = vws + 2 * 512 * 3136;             // total 16,056,320 B

    qkv_kernel<<<dim3(49, 12, 2), 256, 0, stream>>>(
        x, wq, sq, bq, wk, sk, bk, wv, sv, bv, qws, kws, vws);
    attn_kernel<<<dim3(16, 196), 256, 0, stream>>>(qws, kws, vws, ows);
    proj_kernel<<<dim3(49, 4, 2), 256, 0, stream>>>(ows, wp, sp, bp, out);
}

// Round 6
// 261.698 us; speedup vs baseline: 1.2149x; 1.2149x over previous
//
#include <hip/hip_runtime.h>

// ============================================================================
// LeViT attention, MI355X. I/O tensors are FLOAT32 (per reference).
// b=2, C=256, H=W=56, n=3136, heads=8, kd=16, dh=64.
// ws layout (u16 bf16 elems): q[2*8*3136*16] | k[same] | v[2*512*3136] | o[same]
//   q,k: [bh][n][16]  (token-major)   v,o: [b][ch][n] (channel-major)
// MFMA 16x16x32_bf16 layouts (HW-verified per guide):
//   A[m=lane&15][k=(lane>>4)*8+j]; B[k=(lane>>4)*8+j][n=lane&15]
//   C/D: col=lane&15, row=(lane>>4)*4+reg
// Round-6 attn: 64 queries/block (wave w owns 16, ALL keys -> no merge).
// K/V staged per 64-key chunk into double-buffered LDS via global_load_lds
// (width 16, async, prefetch chunk c+1 during compute of c). V octet-swizzled
// (pos = oct ^ (d&7)) so PV B-frag ds_read_b128 is conflict-free (padding is
// impossible under the lane*16 scatter). L2 traffic 1.9GB -> ~0.4GB.
// ============================================================================

typedef short  s16x8 __attribute__((ext_vector_type(8)));
typedef float  f32x4 __attribute__((ext_vector_type(4)));
typedef unsigned short u16;
typedef unsigned short u16x4 __attribute__((ext_vector_type(4)));

__device__ __forceinline__ float bf2f(u16 v) {
    unsigned u = ((unsigned)v) << 16;
    return __builtin_bit_cast(float, u);
}
__device__ __forceinline__ u16 f2bf(float f) {   // RNE
    unsigned u = __builtin_bit_cast(unsigned, f);
    u += 0x7FFF + ((u >> 16) & 1);
    return (u16)(u >> 16);
}

__device__ __forceinline__ void stage16(const u16* g, u16* l) {
    __builtin_amdgcn_global_load_lds(
        (const __attribute__((address_space(1))) unsigned int*)g,
        (__attribute__((address_space(3))) unsigned int*)l, 16, 0, 0);
}

// ---------------------------------------------------------------------------
// Kernel 1: QKV projection (fp32 in, bf16 ws out).  [unchanged]
// ---------------------------------------------------------------------------
__global__ __launch_bounds__(256) void qkv_kernel(
    const float* __restrict__ x,
    const float* __restrict__ wq, const float* __restrict__ sq, const float* __restrict__ bq,
    const float* __restrict__ wk, const float* __restrict__ sk, const float* __restrict__ bk,
    const float* __restrict__ wv, const float* __restrict__ sv, const float* __restrict__ bv,
    u16* __restrict__ qws, u16* __restrict__ kws, u16* __restrict__ vws)
{
    const int b  = blockIdx.z;
    const int rt = blockIdx.y;
    const int n0 = blockIdx.x * 64;

    const float *W, *Sc, *Bi; int row0, kind;
    if (rt < 2)      { W = wq; Sc = sq; Bi = bq; row0 = rt * 64;       kind = 0; }
    else if (rt < 4) { W = wk; Sc = sk; Bi = bk; row0 = (rt - 2) * 64; kind = 1; }
    else             { W = wv; Sc = sv; Bi = bv; row0 = (rt - 4) * 64; kind = 2; }

    __shared__ float As[16][64];
    __shared__ float Bs[16][64];

    const int t  = threadIdx.x;
    const int tm = t >> 4, tn = t & 15;
    const int am = t >> 2, ak = (t & 3) * 4;
    const int bn = t & 63, bk0 = (t >> 6) * 4;

    float acc[4][4];
    #pragma unroll
    for (int i = 0; i < 4; i++)
        #pragma unroll
        for (int j = 0; j < 4; j++) acc[i][j] = 0.f;

    for (int kc = 0; kc < 256; kc += 16) {
        f32x4 w4 = *(const f32x4*)&W[(row0 + am) * 256 + kc + ak];
        #pragma unroll
        for (int j = 0; j < 4; j++) As[ak + j][am] = w4[j];
        #pragma unroll
        for (int j = 0; j < 4; j++)
            Bs[bk0 + j][bn] = x[(b * 256 + kc + bk0 + j) * 3136 + n0 + bn];
        __syncthreads();
        #pragma unroll
        for (int kk = 0; kk < 16; kk++) {
            f32x4 a  = *(const f32x4*)&As[kk][tm * 4];
            f32x4 bb = *(const f32x4*)&Bs[kk][tn * 4];
            #pragma unroll
            for (int i = 0; i < 4; i++)
                #pragma unroll
                for (int j = 0; j < 4; j++) acc[i][j] = fmaf(a[i], bb[j], acc[i][j]);
        }
        __syncthreads();
    }

    #pragma unroll
    for (int i = 0; i < 4; i++) {
        const int ocl = row0 + tm * 4 + i;
        const float sc = Sc[ocl], bi = Bi[ocl];
        if (kind == 2) {
            u16x4 o4;
            #pragma unroll
            for (int j = 0; j < 4; j++) o4[j] = f2bf(acc[i][j] * sc + bi);
            *(u16x4*)&vws[(b * 512 + ocl) * 3136 + n0 + tn * 4] = o4;
        } else {
            u16* dst = (kind == 0) ? qws : kws;
            const int h = ocl >> 4, d = ocl & 15;
            #pragma unroll
            for (int j = 0; j < 4; j++) {
                const int n = n0 + tn * 4 + j;
                dst[((b * 8 + h) * 3136 + n) * 16 + d] = f2bf(acc[i][j] * sc + bi);
            }
        }
    }
}

// ---------------------------------------------------------------------------
// Kernel 2: flash attention v5. grid (16 bh, 49 q-tiles of 64); block 256.
// Wave w owns queries tile*64+w*16..+16, iterates all 49 key-chunks of 64.
// K/V staged cooperatively into double-buffered LDS (async global_load_lds).
// ---------------------------------------------------------------------------
__global__ __launch_bounds__(256, 4) void attn_kernel(
    const u16* __restrict__ qws, const u16* __restrict__ kws,
    const u16* __restrict__ vws, u16* __restrict__ ows)
{
    const int bh   = blockIdx.x;                 // x fastest -> XCD = bh%8
    const int tile = blockIdx.y;
    const int t    = threadIdx.x;
    const int wave = t >> 6, lane = t & 63;
    const int l15  = lane & 15, quad = lane >> 4;
    const int kq   = quad & 1;
    const int nb   = tile * 64 + wave * 16;      // this wave's query base

    __shared__ __align__(16) u16 kbuf[2][1024];      // [key][ch] 64x16
    __shared__ __align__(16) u16 vbuf[2][4096];      // [d][oct-swizzled key] 64x64
    __shared__ __align__(16) u16 pbuf[4][16 * 68];   // per-wave P transpose
    u16* pw = &pbuf[wave][0];

    const u16* kb = &kws[bh * 3136 * 16];
    const u16* vb = &vws[bh * 64 * 3136];        // (b*512+h*64) == bh*64
    const float L2E = 1.44269504088896f;

    // staging source addresses (per lane, chunk-invariant parts)
    const int vd   = (lane >> 3);                // d within 8-row segment
    const int voct = (lane & 7) ^ vd;            // swizzled octet position
    const int kkey = lane >> 1, khalf = lane & 1;

    // ---- stage chunk 0 into buffer 0
    {
        #pragma unroll
        for (int s = 0; s < 2; s++) {
            const int seg = wave + s * 4;
            stage16(vb + (seg * 8 + vd) * 3136 + 0 + voct * 8, &vbuf[0][seg * 512]);
        }
        if (wave < 2)
            stage16(kb + (wave * 32 + kkey) * 16 + khalf * 8, &kbuf[0][wave * 512]);
    }

    // Q fragment: A[m=l15][k=quad*8+j]; kd=16 padded to K=32 with zeros
    s16x8 aq = {0, 0, 0, 0, 0, 0, 0, 0};
    if (quad < 2)
        aq = *(const s16x8*)&qws[(bh * 3136 + nb + l15) * 16 + quad * 8];

    float rsum[4] = {0.f, 0.f, 0.f, 0.f};
    f32x4 acc[4];
    #pragma unroll
    for (int dt = 0; dt < 4; dt++) acc[dt] = (f32x4){0.f, 0.f, 0.f, 0.f};

    __builtin_amdgcn_s_waitcnt(0x0f70);          // vmcnt(0)
    __syncthreads();

    for (int c = 0; c < 49; c++) {
        const int cur = c & 1, nxt = cur ^ 1;
        const int k0n = (c + 1 < 49) ? (c + 1) * 64 : c * 64;

        // ---- stage chunk c+1 into the other buffer (async)
        #pragma unroll
        for (int s = 0; s < 2; s++) {
            const int seg = wave + s * 4;
            stage16(vb + (seg * 8 + vd) * 3136 + k0n + voct * 8, &vbuf[nxt][seg * 512]);
        }
        if (wave < 2)
            stage16(kb + (k0n + wave * 32 + kkey) * 16 + khalf * 8, &kbuf[nxt][wave * 512]);

        // ---- S = Q*K^T : 4 key sub-tiles of 16 (K frags from LDS)
        const u16* kc_ = kbuf[cur];
        const u16* vc_ = vbuf[cur];
        const f32x4 z = {0.f, 0.f, 0.f, 0.f};
        f32x4 s[4];
        #pragma unroll
        for (int i = 0; i < 4; i++) {
            s16x8 kf = *(const s16x8*)&kc_[(i * 16 + l15) * 16 + kq * 8];
            s[i] = __builtin_amdgcn_mfma_f32_16x16x32_bf16(aq, kf, z, 0, 0, 0);
        }

        // ---- P = exp2(S*log2e) -> bf16 into per-wave LDS (C-layout rows)
        #pragma unroll
        for (int i = 0; i < 4; i++) {
            #pragma unroll
            for (int r = 0; r < 4; r++) {
                const float p = __builtin_amdgcn_exp2f(s[i][r] * L2E);
                rsum[r] += p;
                pw[(quad * 4 + r) * 68 + i * 16 + l15] = f2bf(p);
            }
        }
        __builtin_amdgcn_wave_barrier();   // in-order DS: writes precede reads

        // ---- A-frags for P (row=query=l15, k=key): raw bf16 b128 reads
        s16x8 ap0 = *(const s16x8*)&pw[l15 * 68 + quad * 8];
        s16x8 ap1 = *(const s16x8*)&pw[l15 * 68 + 32 + quad * 8];
        __builtin_amdgcn_wave_barrier();   // reads precede next iter's writes

        // ---- O += P*V ; B-frag V[d=dt*16+l15][key oct (g*4+quad)^(l15&7)]
        #pragma unroll
        for (int dt = 0; dt < 4; dt++) {
            const int row = (dt * 16 + l15) * 64;
            s16x8 v0 = *(const s16x8*)&vc_[row + ((quad ^ (l15 & 7)) * 8)];
            s16x8 v1 = *(const s16x8*)&vc_[row + (((4 + quad) ^ (l15 & 7)) * 8)];
            acc[dt] = __builtin_amdgcn_mfma_f32_16x16x32_bf16(ap0, v0, acc[dt], 0, 0, 0);
            acc[dt] = __builtin_amdgcn_mfma_f32_16x16x32_bf16(ap1, v1, acc[dt], 0, 0, 0);
        }

        __builtin_amdgcn_s_waitcnt(0x0f70);      // drain my staging (vmcnt 0)
        __syncthreads();                          // all staging visible
    }

    // ---- rowsum reduction over the 16 key-lanes of each quad
    #pragma unroll
    for (int r = 0; r < 4; r++) {
        #pragma unroll
        for (int off = 8; off >= 1; off >>= 1)
            rsum[r] += __shfl_xor(rsum[r], off, 64);
        rsum[r] = 1.0f / rsum[r];
    }

    #pragma unroll
    for (int dt = 0; dt < 4; dt++) {
        u16x4 o4;
        #pragma unroll
        for (int r = 0; r < 4; r++) o4[r] = f2bf(acc[dt][r] * rsum[r]);
        // C-layout: col=d_local, rows = 4 consecutive queries -> 8B store
        *(u16x4*)&ows[(bh * 64 + dt * 16 + l15) * 3136 + nb + quad * 4] = o4;
    }
}

// ---------------------------------------------------------------------------
// Kernel 3: output projection (bf16 ws in, fp32 out).  [unchanged]
// ---------------------------------------------------------------------------
__global__ __launch_bounds__(256) void proj_kernel(
    const u16* __restrict__ ows, const float* __restrict__ wp,
    const float* __restrict__ sp, const float* __restrict__ bp,
    float* __restrict__ out)
{
    const int b  = blockIdx.z;
    const int n0 = blockIdx.x * 64;
    const int row0 = blockIdx.y * 64;

    __shared__ float As[16][64];
    __shared__ float Bs[16][64];

    const int t  = threadIdx.x;
    const int tm = t >> 4, tn = t & 15;
    const int am = t >> 2, ak = (t & 3) * 4;
    const int bn = t & 63, bk0 = (t >> 6) * 4;

    float acc[4][4];
    #pragma unroll
    for (int i = 0; i < 4; i++)
        #pragma unroll
        for (int j = 0; j < 4; j++) acc[i][j] = 0.f;

    for (int kc = 0; kc < 512; kc += 16) {
        f32x4 w4 = *(const f32x4*)&wp[(row0 + am) * 512 + kc + ak];
        #pragma unroll
        for (int j = 0; j < 4; j++) As[ak + j][am] = w4[j];
        #pragma unroll
        for (int j = 0; j < 4; j++)
            Bs[bk0 + j][bn] = bf2f(ows[(b * 512 + kc + bk0 + j) * 3136 + n0 + bn]);
        __syncthreads();
        #pragma unroll
        for (int kk = 0; kk < 16; kk++) {
            f32x4 a  = *(const f32x4*)&As[kk][tm * 4];
            f32x4 bb = *(const f32x4*)&Bs[kk][tn * 4];
            #pragma unroll
            for (int i = 0; i < 4; i++)
                #pragma unroll
                for (int j = 0; j < 4; j++) acc[i][j] = fmaf(a[i], bb[j], acc[i][j]);
        }
        __syncthreads();
    }

    #pragma unroll
    for (int i = 0; i < 4; i++) {
        const int oc = row0 + tm * 4 + i;
        const float sc = sp[oc], bi = bp[oc];
        f32x4 o4;
        #pragma unroll
        for (int j = 0; j < 4; j++) o4[j] = acc[i][j] * sc + bi;
        *(f32x4*)&out[(b * 256 + oc) * 3136 + n0 + tn * 4] = o4;
    }
}

// ---------------------------------------------------------------------------
extern "C" void kernel_launch(void* const* d_in, const int* in_sizes, int n_in,
                              void* d_out, int out_size, void* d_ws, size_t ws_size,
                              hipStream_t stream) {
    const float* x  = (const float*)d_in[0];
    const float* wq = (const float*)d_in[1];
    const float* sq = (const float*)d_in[2];
    const float* bq = (const float*)d_in[3];
    const float* wk = (const float*)d_in[4];
    const float* sk = (const float*)d_in[5];
    const float* bk = (const float*)d_in[6];
    const float* wv = (const float*)d_in[7];
    const float* sv = (const float*)d_in[8];
    const float* bv = (const float*)d_in[9];
    const float* wp = (const float*)d_in[10];
    const float* sp = (const float*)d_in[11];
    const float* bp = (const float*)d_in[12];
    float* out = (float*)d_out;

    u16* qws = (u16*)d_ws;                       // 2*8*3136*16 = 802816
    u16* kws = qws + 2 * 8 * 3136 * 16;
    u16* vws = kws + 2 * 8 * 3136 * 16;          // 2*512*3136 = 3211264
    u16* ows = vws + 2 * 512 * 3136;             // total 16,056,320 B

    qkv_kernel<<<dim3(49, 12, 2), 256, 0, stream>>>(
        x, wq, sq, bq, wk, sk, bk, wv, sv, bv, qws, kws, vws);
    attn_kernel<<<dim3(16, 49), 256, 0, stream>>>(qws, kws, vws, ows);
    proj_kernel<<<dim3(49, 4, 2), 256, 0, stream>>>(ows, wp, sp, bp, out);
}

// Round 7
// 244.014 us; speedup vs baseline: 1.3029x; 1.0725x over previous
//
#include <hip/hip_runtime.h>

// ============================================================================
// LeViT attention, MI355X. I/O tensors are FLOAT32 (per reference).
// b=2, C=256, H=W=56, n=3136, heads=8, kd=16, dh=64.
// Pipeline: xt (x->x_t bf16 token-major) + wconv (W'=s*W bf16) -> qkv (MFMA,
// no LDS) -> attn (flash, LDS-staged K/V, writes o_t token-major) -> proj
// (MFMA, no LDS, fp32 out).
// ws (u16 elems): qws 802816 | kws 802816 | vws 3211264 | R 3211264
//   (R = x_t[2*3136*256] during xt/qkv, o_t[2*3136*512] from attn on)
//   | wqb 32768 | wkb 32768 | wvb 131072 | wpb 131072   => 16,711,680 B
// MFMA 16x16x32_bf16: A[m=l15][k=quad*8+j]; B[k=quad*8+j][n=l15];
// C/D: col=l15, row=quad*4+reg.
// ============================================================================

typedef short  s16x8 __attribute__((ext_vector_type(8)));
typedef float  f32x4 __attribute__((ext_vector_type(4)));
typedef unsigned short u16;
typedef unsigned short u16x8 __attribute__((ext_vector_type(8)));

__device__ __forceinline__ u16 f2bf(float f) {   // RNE
    unsigned u = __builtin_bit_cast(unsigned, f);
    u += 0x7FFF + ((u >> 16) & 1);
    return (u16)(u >> 16);
}
__device__ __forceinline__ f32x4 mfma16(s16x8 a, s16x8 b, f32x4 c) {
    return __builtin_amdgcn_mfma_f32_16x16x32_bf16(a, b, c, 0, 0, 0);
}
__device__ __forceinline__ void stage16(const u16* g, u16* l) {
    __builtin_amdgcn_global_load_lds(
        (const __attribute__((address_space(1))) unsigned int*)g,
        (__attribute__((address_space(3))) unsigned int*)l, 16, 0, 0);
}

// ---------------------------------------------------------------------------
// x [b][256][3136] fp32 -> x_t [b][3136][256] bf16. grid (49,4,2), 256 thr.
// ---------------------------------------------------------------------------
__global__ __launch_bounds__(256) void xt_kernel(
    const float* __restrict__ x, u16* __restrict__ xt)
{
    const int b = blockIdx.z, c0 = blockIdx.y * 64, n0 = blockIdx.x * 64;
    __shared__ float lds[64][65];
    const int t = threadIdx.x, nl = t & 63, cl = t >> 6;
    #pragma unroll
    for (int i = 0; i < 16; i++) {
        const int c = cl + i * 4;
        lds[c][nl] = x[(b * 256 + c0 + c) * 3136 + n0 + nl];
    }
    __syncthreads();
    #pragma unroll
    for (int i = 0; i < 16; i++) {
        const int n = cl + i * 4;
        xt[(b * 3136 + n0 + n) * 256 + c0 + nl] = f2bf(lds[nl][n]);
    }
}

// ---------------------------------------------------------------------------
// W' = s*W in bf16 for all four weight arrays. grid (320), 256 thr.
// ---------------------------------------------------------------------------
__global__ __launch_bounds__(256) void wconv_kernel(
    const float* __restrict__ wq, const float* __restrict__ sq,
    const float* __restrict__ wk, const float* __restrict__ sk,
    const float* __restrict__ wv, const float* __restrict__ sv,
    const float* __restrict__ wp, const float* __restrict__ sp,
    u16* __restrict__ wqb, u16* __restrict__ wkb,
    u16* __restrict__ wvb, u16* __restrict__ wpb)
{
    for (int idx = blockIdx.x * 256 + threadIdx.x; idx < 327680; idx += 81920) {
        if (idx < 32768)        wqb[idx] = f2bf(wq[idx] * sq[idx >> 8]);
        else if (idx < 65536)  { int j = idx - 32768;  wkb[j] = f2bf(wk[j] * sk[j >> 8]); }
        else if (idx < 196608) { int j = idx - 65536;  wvb[j] = f2bf(wv[j] * sv[j >> 8]); }
        else                   { int j = idx - 196608; wpb[j] = f2bf(wp[j] * sp[j >> 9]); }
    }
}

// ---------------------------------------------------------------------------
// QKV MFMA GEMM, no LDS. grid (49 n-tiles, 12 rt, 2 b), 256 thr.
// rt 0..3: q/k (C[token][och], token-major store); rt 4..11: v (C[och][token]).
// ---------------------------------------------------------------------------
__global__ __launch_bounds__(256, 4) void qkv_kernel(
    const u16* __restrict__ xt,
    const u16* __restrict__ wqb, const u16* __restrict__ wkb, const u16* __restrict__ wvb,
    const float* __restrict__ bq, const float* __restrict__ bk, const float* __restrict__ bv,
    u16* __restrict__ qws, u16* __restrict__ kws, u16* __restrict__ vws)
{
    const int b = blockIdx.z, rt = blockIdx.y, n0 = blockIdx.x * 64;
    const int t = threadIdx.x, wave = t >> 6, lane = t & 63;
    const int l15 = lane & 15, quad = lane >> 4;
    const f32x4 z = {0.f, 0.f, 0.f, 0.f};

    if (rt < 4) {
        // ---- nw-mode: A = x_t (m=token), B = W' (n=och). q: rt<2, k: rt>=2.
        const u16* wb      = (rt < 2) ? wqb : wkb;
        const float* bias  = (rt < 2) ? bq : bk;
        u16* dst           = (rt < 2) ? qws : kws;
        const int och0 = (rt & 1) * 64;
        const int m0   = n0 + wave * 16;
        const u16* xrow = &xt[(b * 3136 + m0 + l15) * 256 + quad * 8];
        f32x4 acc[4] = {z, z, z, z};
        #pragma unroll
        for (int kc = 0; kc < 256; kc += 32) {
            s16x8 a = *(const s16x8*)&xrow[kc];
            #pragma unroll
            for (int f = 0; f < 4; f++) {
                s16x8 bf = *(const s16x8*)&wb[(och0 + f * 16 + l15) * 256 + kc + quad * 8];
                acc[f] = mfma16(a, bf, acc[f]);
            }
        }
        #pragma unroll
        for (int f = 0; f < 4; f++) {
            const int och = och0 + f * 16 + l15;       // d = l15, h = och>>4
            const float bi = bias[och];
            const int h = och >> 4;
            #pragma unroll
            for (int r = 0; r < 4; r++) {
                const int tok = m0 + quad * 4 + r;
                dst[((b * 8 + h) * 3136 + tok) * 16 + l15] = f2bf(acc[f][r] + bi);
            }
        }
    } else {
        // ---- wn-mode: A = W'v (m=och), B = x_t (n=token). C[och][token].
        const int och0 = (rt - 4) * 64 + wave * 16;
        const u16* arow = &wvb[(och0 + l15) * 256 + quad * 8];
        f32x4 acc[4] = {z, z, z, z};
        #pragma unroll
        for (int kc = 0; kc < 256; kc += 32) {
            s16x8 a = *(const s16x8*)&arow[kc];
            #pragma unroll
            for (int f = 0; f < 4; f++) {
                s16x8 bf = *(const s16x8*)&xt[(b * 3136 + n0 + f * 16 + l15) * 256 + kc + quad * 8];
                acc[f] = mfma16(a, bf, acc[f]);
            }
        }
        #pragma unroll
        for (int r = 0; r < 4; r++) {
            const int och = och0 + quad * 4 + r;
            const float bi = bv[och];
            #pragma unroll
            for (int f = 0; f < 4; f++) {
                const int tok = n0 + f * 16 + l15;
                vws[(b * 512 + och) * 3136 + tok] = f2bf(acc[f][r] + bi);
            }
        }
    }
}

// ---------------------------------------------------------------------------
// Flash attention. grid (16 bh, 49 q-tiles of 64); 4 waves; 49 key-chunks of
// 64 staged into double-buffered LDS. Epilogue writes o_t[b][n][512] via an
// LDS transpose reusing the staging buffers.
// ---------------------------------------------------------------------------
__global__ __launch_bounds__(256, 4) void attn_kernel(
    const u16* __restrict__ qws, const u16* __restrict__ kws,
    const u16* __restrict__ vws, u16* __restrict__ o_t)
{
    const int bh   = blockIdx.x;                 // x fastest -> XCD = bh%8
    const int tile = blockIdx.y;
    const int t    = threadIdx.x;
    const int wave = t >> 6, lane = t & 63;
    const int l15  = lane & 15, quad = lane >> 4;
    const int kq   = quad & 1;
    const int nb   = tile * 64 + wave * 16;      // this wave's query base

    __shared__ __align__(16) u16 stg[2][5120];       // per buf: K 1024 | V 4096
    __shared__ __align__(16) u16 pbuf[4][16 * 68];   // per-wave P transpose
    u16* pw = &pbuf[wave][0];

    const u16* kb = &kws[bh * 3136 * 16];
    const u16* vb = &vws[bh * 64 * 3136];
    const float L2E = 1.44269504088896f;

    const int vd   = (lane >> 3);
    const int voct = (lane & 7) ^ vd;
    const int kkey = lane >> 1, khalf = lane & 1;

    // ---- stage chunk 0 into buffer 0
    #pragma unroll
    for (int s = 0; s < 2; s++) {
        const int seg = wave + s * 4;
        stage16(vb + (seg * 8 + vd) * 3136 + voct * 8, &stg[0][1024 + seg * 512]);
    }
    if (wave < 2)
        stage16(kb + (wave * 32 + kkey) * 16 + khalf * 8, &stg[0][wave * 512]);

    s16x8 aq = {0, 0, 0, 0, 0, 0, 0, 0};
    if (quad < 2)
        aq = *(const s16x8*)&qws[(bh * 3136 + nb + l15) * 16 + quad * 8];

    float rsum[4] = {0.f, 0.f, 0.f, 0.f};
    f32x4 acc[4];
    #pragma unroll
    for (int dt = 0; dt < 4; dt++) acc[dt] = (f32x4){0.f, 0.f, 0.f, 0.f};

    __builtin_amdgcn_s_waitcnt(0x0f70);          // vmcnt(0)
    __syncthreads();

    for (int c = 0; c < 49; c++) {
        const int cur = c & 1, nxt = cur ^ 1;
        const int k0n = (c + 1 < 49) ? (c + 1) * 64 : c * 64;

        #pragma unroll
        for (int s = 0; s < 2; s++) {
            const int seg = wave + s * 4;
            stage16(vb + (seg * 8 + vd) * 3136 + k0n + voct * 8, &stg[nxt][1024 + seg * 512]);
        }
        if (wave < 2)
            stage16(kb + (k0n + wave * 32 + kkey) * 16 + khalf * 8, &stg[nxt][wave * 512]);

        const u16* kc_ = &stg[cur][0];
        const u16* vc_ = &stg[cur][1024];
        const f32x4 z = {0.f, 0.f, 0.f, 0.f};
        f32x4 s[4];
        #pragma unroll
        for (int i = 0; i < 4; i++) {
            s16x8 kf = *(const s16x8*)&kc_[(i * 16 + l15) * 16 + kq * 8];
            s[i] = mfma16(aq, kf, z);
        }

        #pragma unroll
        for (int i = 0; i < 4; i++) {
            #pragma unroll
            for (int r = 0; r < 4; r++) {
                const float p = __builtin_amdgcn_exp2f(s[i][r] * L2E);
                rsum[r] += p;
                pw[(quad * 4 + r) * 68 + i * 16 + l15] = f2bf(p);
            }
        }
        __builtin_amdgcn_wave_barrier();

        s16x8 ap0 = *(const s16x8*)&pw[l15 * 68 + quad * 8];
        s16x8 ap1 = *(const s16x8*)&pw[l15 * 68 + 32 + quad * 8];
        __builtin_amdgcn_wave_barrier();

        #pragma unroll
        for (int dt = 0; dt < 4; dt++) {
            const int row = (dt * 16 + l15) * 64;
            s16x8 v0 = *(const s16x8*)&vc_[1024 * 0 + row + ((quad ^ (l15 & 7)) * 8)];
            s16x8 v1 = *(const s16x8*)&vc_[row + (((4 + quad) ^ (l15 & 7)) * 8)];
            acc[dt] = mfma16(ap0, v0, acc[dt]);
            acc[dt] = mfma16(ap1, v1, acc[dt]);
        }

        __builtin_amdgcn_s_waitcnt(0x0f70);      // drain staging
        __syncthreads();
    }

    // ---- rowsum reduce + invert
    #pragma unroll
    for (int r = 0; r < 4; r++) {
        #pragma unroll
        for (int off = 8; off >= 1; off >>= 1)
            rsum[r] += __shfl_xor(rsum[r], off, 64);
        rsum[r] = 1.0f / rsum[r];
    }

    // ---- epilogue: transpose C-layout -> o_t[b][n][512] via stg (loop done)
    float* ob = (float*)((char*)&stg[0][0] + wave * 4352);   // [16 tok][68] f32
    #pragma unroll
    for (int dt = 0; dt < 4; dt++)
        #pragma unroll
        for (int r = 0; r < 4; r++)
            ob[(quad * 4 + r) * 68 + dt * 16 + l15] = acc[dt][r] * rsum[r];
    __builtin_amdgcn_wave_barrier();

    const int q  = lane & 15;                    // token-within-16
    const int qt = lane >> 4;                    // d-quarter
    f32x4 o0 = *(const f32x4*)&ob[q * 68 + qt * 16 + 0];
    f32x4 o1 = *(const f32x4*)&ob[q * 68 + qt * 16 + 4];
    f32x4 o2 = *(const f32x4*)&ob[q * 68 + qt * 16 + 8];
    f32x4 o3 = *(const f32x4*)&ob[q * 68 + qt * 16 + 12];
    u16x8 w0, w1;
    #pragma unroll
    for (int i = 0; i < 4; i++) {
        w0[i] = f2bf(o0[i]); w0[4 + i] = f2bf(o1[i]);
        w1[i] = f2bf(o2[i]); w1[4 + i] = f2bf(o3[i]);
    }
    const int n_glob = tile * 64 + wave * 16 + q;
    u16* dst = &o_t[(((bh >> 3) * 3136) + n_glob) * 512 + (bh & 7) * 64 + qt * 16];
    *(u16x8*)&dst[0] = w0;
    *(u16x8*)&dst[8] = w1;
}

// ---------------------------------------------------------------------------
// Output projection MFMA GEMM, no LDS. grid (98 n-tiles of 32, 4 och, 2 b).
// A = wp' [256][512], B = o_t [n][512]; C[och][token] -> fp32 out.
// ---------------------------------------------------------------------------
__global__ __launch_bounds__(256, 4) void proj_kernel(
    const u16* __restrict__ o_t, const u16* __restrict__ wpb,
    const float* __restrict__ bp, float* __restrict__ out)
{
    const int b = blockIdx.z, n0 = blockIdx.x * 32;
    const int och0 = blockIdx.y * 64 + (threadIdx.x >> 6) * 16;
    const int lane = threadIdx.x & 63;
    const int l15 = lane & 15, quad = lane >> 4;
    const f32x4 z = {0.f, 0.f, 0.f, 0.f};

    const u16* arow = &wpb[(och0 + l15) * 512 + quad * 8];
    f32x4 acc[2] = {z, z};
    #pragma unroll 4
    for (int kc = 0; kc < 512; kc += 32) {
        s16x8 a = *(const s16x8*)&arow[kc];
        #pragma unroll
        for (int f = 0; f < 2; f++) {
            s16x8 bf = *(const s16x8*)&o_t[(b * 3136 + n0 + f * 16 + l15) * 512 + kc + quad * 8];
            acc[f] = mfma16(a, bf, acc[f]);
        }
    }
    #pragma unroll
    for (int r = 0; r < 4; r++) {
        const int och = och0 + quad * 4 + r;
        const float bi = bp[och];
        #pragma unroll
        for (int f = 0; f < 2; f++)
            out[(b * 256 + och) * 3136 + n0 + f * 16 + l15] = acc[f][r] + bi;
    }
}

// ---------------------------------------------------------------------------
extern "C" void kernel_launch(void* const* d_in, const int* in_sizes, int n_in,
                              void* d_out, int out_size, void* d_ws, size_t ws_size,
                              hipStream_t stream) {
    const float* x  = (const float*)d_in[0];
    const float* wq = (const float*)d_in[1];
    const float* sq = (const float*)d_in[2];
    const float* bq = (const float*)d_in[3];
    const float* wk = (const float*)d_in[4];
    const float* sk = (const float*)d_in[5];
    const float* bk = (const float*)d_in[6];
    const float* wv = (const float*)d_in[7];
    const float* sv = (const float*)d_in[8];
    const float* bv = (const float*)d_in[9];
    const float* wp = (const float*)d_in[10];
    const float* sp = (const float*)d_in[11];
    const float* bp = (const float*)d_in[12];
    float* out = (float*)d_out;

    u16* qws = (u16*)d_ws;                 // 802816
    u16* kws = qws + 802816;               // 802816
    u16* vws = kws + 802816;               // 3211264
    u16* R   = vws + 3211264;              // 3211264 (x_t then o_t, overlaid)
    u16* xt  = R;
    u16* ot  = R;
    u16* wqb = R + 3211264;                // 32768
    u16* wkb = wqb + 32768;                // 32768
    u16* wvb = wkb + 32768;                // 131072
    u16* wpb = wvb + 131072;               // 131072  (total 16,711,680 B)

    xt_kernel<<<dim3(49, 4, 2), 256, 0, stream>>>(x, xt);
    wconv_kernel<<<dim3(320), 256, 0, stream>>>(wq, sq, wk, sk, wv, sv, wp, sp,
                                                wqb, wkb, wvb, wpb);
    qkv_kernel<<<dim3(49, 12, 2), 256, 0, stream>>>(xt, wqb, wkb, wvb,
                                                    bq, bk, bv, qws, kws, vws);
    attn_kernel<<<dim3(16, 49), 256, 0, stream>>>(qws, kws, vws, ot);
    proj_kernel<<<dim3(98, 4, 2), 256, 0, stream>>>(ot, wpb, bp, out);
}

// Round 8
// 206.673 us; speedup vs baseline: 1.5383x; 1.1807x over previous
//
#include <hip/hip_runtime.h>

// ============================================================================
// LeViT attention, MI355X. I/O tensors are FLOAT32 (per reference).
// b=2, C=256, H=W=56, n=3136, heads=8, kd=16, dh=64.
// Pipeline: xt (x->x_t bf16 token-major) + wconv (W'=s*W bf16) -> qkv (MFMA,
// no LDS) -> attn (flash, operand-swapped MFMA, triple-buffered staging,
// single s_barrier + vmcnt(3) per chunk) -> proj (MFMA, no LDS, fp32 out).
// ws (u16 elems): qws 802816 | kws 802816 | vws 3211264 | R 3211264
//   (R = x_t[2*3136*256] during xt/qkv, o_t[2*3136*512] from attn on)
//   | wqb 32768 | wkb 32768 | wvb 131072 | wpb 131072   => 16,711,680 B
// MFMA 16x16x32_bf16: A[m=l15][k=quad*8+j]; B[k=quad*8+j][n=l15];
// MFMA 16x16x16bf16_1k: A[m=l15][k=quad*4+j]; B[k=quad*4+j][n=l15];
// C/D (both): col=l15, row=quad*4+reg.
// attn: S^T = mfma32(A=K,B=Q) -> C rows=key,cols=query; exp+pack = PV B-frag
// directly (no LDS transpose); O^T = mfma16(A=V^T,B=P) -> direct stores.
// ============================================================================

typedef short  s16x8 __attribute__((ext_vector_type(8)));
typedef short  s16x4 __attribute__((ext_vector_type(4)));
typedef float  f32x4 __attribute__((ext_vector_type(4)));
typedef unsigned short u16;
typedef unsigned short u16x4 __attribute__((ext_vector_type(4)));
typedef unsigned short u16x8 __attribute__((ext_vector_type(8)));

__device__ __forceinline__ u16 f2bf(float f) {   // RNE
    unsigned u = __builtin_bit_cast(unsigned, f);
    u += 0x7FFF + ((u >> 16) & 1);
    return (u16)(u >> 16);
}
__device__ __forceinline__ f32x4 mfma32(s16x8 a, s16x8 b, f32x4 c) {
    return __builtin_amdgcn_mfma_f32_16x16x32_bf16(a, b, c, 0, 0, 0);
}
__device__ __forceinline__ f32x4 mfma16(s16x4 a, s16x4 b, f32x4 c) {
    return __builtin_amdgcn_mfma_f32_16x16x16bf16_1k(a, b, c, 0, 0, 0);
}
__device__ __forceinline__ void stage16(const u16* g, u16* l) {
    __builtin_amdgcn_global_load_lds(
        (const __attribute__((address_space(1))) unsigned int*)g,
        (__attribute__((address_space(3))) unsigned int*)l, 16, 0, 0);
}

// ---------------------------------------------------------------------------
// x [b][256][3136] fp32 -> x_t [b][3136][256] bf16. grid (49,4,2), 256 thr.
// ---------------------------------------------------------------------------
__global__ __launch_bounds__(256) void xt_kernel(
    const float* __restrict__ x, u16* __restrict__ xt)
{
    const int b = blockIdx.z, c0 = blockIdx.y * 64, n0 = blockIdx.x * 64;
    __shared__ float lds[64][65];
    const int t = threadIdx.x, nl = t & 63, cl = t >> 6;
    #pragma unroll
    for (int i = 0; i < 16; i++) {
        const int c = cl + i * 4;
        lds[c][nl] = x[(b * 256 + c0 + c) * 3136 + n0 + nl];
    }
    __syncthreads();
    #pragma unroll
    for (int i = 0; i < 16; i++) {
        const int n = cl + i * 4;
        xt[(b * 3136 + n0 + n) * 256 + c0 + nl] = f2bf(lds[nl][n]);
    }
}

// ---------------------------------------------------------------------------
// W' = s*W in bf16 for all four weight arrays. grid (320), 256 thr.
// ---------------------------------------------------------------------------
__global__ __launch_bounds__(256) void wconv_kernel(
    const float* __restrict__ wq, const float* __restrict__ sq,
    const float* __restrict__ wk, const float* __restrict__ sk,
    const float* __restrict__ wv, const float* __restrict__ sv,
    const float* __restrict__ wp, const float* __restrict__ sp,
    u16* __restrict__ wqb, u16* __restrict__ wkb,
    u16* __restrict__ wvb, u16* __restrict__ wpb)
{
    for (int idx = blockIdx.x * 256 + threadIdx.x; idx < 327680; idx += 81920) {
        if (idx < 32768)        wqb[idx] = f2bf(wq[idx] * sq[idx >> 8]);
        else if (idx < 65536)  { int j = idx - 32768;  wkb[j] = f2bf(wk[j] * sk[j >> 8]); }
        else if (idx < 196608) { int j = idx - 65536;  wvb[j] = f2bf(wv[j] * sv[j >> 8]); }
        else                   { int j = idx - 196608; wpb[j] = f2bf(wp[j] * sp[j >> 9]); }
    }
}

// ---------------------------------------------------------------------------
// QKV MFMA GEMM, no LDS. grid (49 n-tiles, 12 rt, 2 b), 256 thr.
// rt 0..3: q/k (C[token][och], token-major store); rt 4..11: v (C[och][token]).
// ---------------------------------------------------------------------------
__global__ __launch_bounds__(256, 4) void qkv_kernel(
    const u16* __restrict__ xt,
    const u16* __restrict__ wqb, const u16* __restrict__ wkb, const u16* __restrict__ wvb,
    const float* __restrict__ bq, const float* __restrict__ bk, const float* __restrict__ bv,
    u16* __restrict__ qws, u16* __restrict__ kws, u16* __restrict__ vws)
{
    const int b = blockIdx.z, rt = blockIdx.y, n0 = blockIdx.x * 64;
    const int t = threadIdx.x, wave = t >> 6, lane = t & 63;
    const int l15 = lane & 15, quad = lane >> 4;
    const f32x4 z = {0.f, 0.f, 0.f, 0.f};

    if (rt < 4) {
        const u16* wb      = (rt < 2) ? wqb : wkb;
        const float* bias  = (rt < 2) ? bq : bk;
        u16* dst           = (rt < 2) ? qws : kws;
        const int och0 = (rt & 1) * 64;
        const int m0   = n0 + wave * 16;
        const u16* xrow = &xt[(b * 3136 + m0 + l15) * 256 + quad * 8];
        f32x4 acc[4] = {z, z, z, z};
        #pragma unroll
        for (int kc = 0; kc < 256; kc += 32) {
            s16x8 a = *(const s16x8*)&xrow[kc];
            #pragma unroll
            for (int f = 0; f < 4; f++) {
                s16x8 bf = *(const s16x8*)&wb[(och0 + f * 16 + l15) * 256 + kc + quad * 8];
                acc[f] = mfma32(a, bf, acc[f]);
            }
        }
        #pragma unroll
        for (int f = 0; f < 4; f++) {
            const int och = och0 + f * 16 + l15;
            const float bi = bias[och];
            const int h = och >> 4;
            #pragma unroll
            for (int r = 0; r < 4; r++) {
                const int tok = m0 + quad * 4 + r;
                dst[((b * 8 + h) * 3136 + tok) * 16 + l15] = f2bf(acc[f][r] + bi);
            }
        }
    } else {
        const int och0 = (rt - 4) * 64 + wave * 16;
        const u16* arow = &wvb[(och0 + l15) * 256 + quad * 8];
        f32x4 acc[4] = {z, z, z, z};
        #pragma unroll
        for (int kc = 0; kc < 256; kc += 32) {
            s16x8 a = *(const s16x8*)&arow[kc];
            #pragma unroll
            for (int f = 0; f < 4; f++) {
                s16x8 bf = *(const s16x8*)&xt[(b * 3136 + n0 + f * 16 + l15) * 256 + kc + quad * 8];
                acc[f] = mfma32(a, bf, acc[f]);
            }
        }
        #pragma unroll
        for (int r = 0; r < 4; r++) {
            const int och = och0 + quad * 4 + r;
            const float bi = bv[och];
            #pragma unroll
            for (int f = 0; f < 4; f++) {
                const int tok = n0 + f * 16 + l15;
                vws[(b * 512 + och) * 3136 + tok] = f2bf(acc[f][r] + bi);
            }
        }
    }
}

// ---------------------------------------------------------------------------
// Flash attention v7. grid (16 bh, 49 q-tiles of 64); 4 waves; 49 key-chunks
// of 64 staged into TRIPLE-buffered LDS. One raw s_barrier + vmcnt(3)/chunk.
// ---------------------------------------------------------------------------
__global__ __launch_bounds__(256, 4) void attn_kernel(
    const u16* __restrict__ qws, const u16* __restrict__ kws,
    const u16* __restrict__ vws, u16* __restrict__ o_t)
{
    const int bh   = blockIdx.x;                 // x fastest -> XCD = bh%8
    const int tile = blockIdx.y;
    const int t    = threadIdx.x;
    const int wave = t >> 6, lane = t & 63;
    const int l15  = lane & 15, quad = lane >> 4;
    const int kq   = quad & 1;
    const int nb   = tile * 64 + wave * 16;      // this wave's query base

    // triple buffer: per buf K 1024 u16 (64 keys x 16d, half-swizzled)
    //                       V 4096 u16 (64 d x 64 keys, octet-swizzled)
    __shared__ __align__(16) u16 stg[3][5120];

    const u16* kb = &kws[bh * 3136 * 16];
    const u16* vb = &vws[bh * 64 * 3136];
    const float L2E = 1.44269504088896f;

    // staging source patterns (dest is always base + lane*16B, wave-uniform)
    const int vd    = lane >> 3;                     // d-row within 8-row seg
    const int voct  = (lane & 7) ^ vd;               // octet swizzle
    const int kkey  = lane >> 1;                     // key within 32-key half
    const int khalf = (lane & 1) ^ ((lane >> 3) & 1);// half swizzle (key bit2)
    const int weff  = wave & 1;                      // waves 0/2, 1/3 dup K

    // Q fragment (B-operand): B[k=d=quad*8+j][n=query=l15]; zero for k>=16
    s16x8 aq = {0, 0, 0, 0, 0, 0, 0, 0};
    if (quad < 2)
        aq = *(const s16x8*)&qws[(bh * 3136 + nb + l15) * 16 + quad * 8];

    float rsum = 0.f;
    f32x4 acc[4];                                // acc[dt]: rows d, col query
    #pragma unroll
    for (int dt = 0; dt < 4; dt++) acc[dt] = (f32x4){0.f, 0.f, 0.f, 0.f};

    // ---- preamble: stage chunks 0,1 into bufs 0,1 (3 loads per wave each)
    #pragma unroll
    for (int c0 = 0; c0 < 2; c0++) {
        const int kbase = c0 * 64;
        #pragma unroll
        for (int s = 0; s < 2; s++) {
            const int seg = wave + s * 4;
            stage16(vb + (seg * 8 + vd) * 3136 + kbase + voct * 8,
                    &stg[c0][1024 + seg * 512]);
        }
        stage16(kb + (kbase + weff * 32 + kkey) * 16 + khalf * 8,
                &stg[c0][weff * 512]);
    }
    __builtin_amdgcn_s_waitcnt(0x0f73);          // vmcnt(3): chunk0 landed (mine)

    for (int c = 0; c < 49; c++) {
        __builtin_amdgcn_s_barrier();            // chunk c certified block-wide;
                                                 // readers of buf (c+2)%3 done
        // ---- stage chunk c+2 (clamped; dead-buffer redundant loads at tail)
        const int cs = (c + 2 < 49) ? (c + 2) : 48;
        const int kbase = cs * 64;
        u16* bufn = stg[(c + 2) % 3];
        #pragma unroll
        for (int s = 0; s < 2; s++) {
            const int seg = wave + s * 4;
            stage16(vb + (seg * 8 + vd) * 3136 + kbase + voct * 8,
                    &bufn[1024 + seg * 512]);
        }
        stage16(kb + (kbase + weff * 32 + kkey) * 16 + khalf * 8,
                &bufn[weff * 512]);
        __builtin_amdgcn_s_waitcnt(0x0f73);      // vmcnt(3): chunk c+1 landed

        const u16* kc_ = &stg[c % 3][0];
        const u16* vc_ = &stg[c % 3][1024];
        const f32x4 z = {0.f, 0.f, 0.f, 0.f};

        // ---- S^T = K·Q^T : 4 key tiles of 16 (swapped operands, verified)
        f32x4 s[4];
        #pragma unroll
        for (int i = 0; i < 4; i++) {
            s16x8 kf = *(const s16x8*)&kc_[(i * 16 + l15) * 16 +
                                           ((kq ^ ((l15 >> 2) & 1)) * 8)];
            s[i] = mfma32(kf, aq, z);
        }

        // ---- P = exp2(S^T*log2e); pack to bf16x4 = PV B-frag (no movement!)
        s16x4 pp[4];
        #pragma unroll
        for (int i = 0; i < 4; i++) {
            #pragma unroll
            for (int r = 0; r < 4; r++) {
                const float p = __builtin_amdgcn_exp2f(s[i][r] * L2E);
                rsum += p;
                pp[i][r] = (short)f2bf(p);
            }
        }

        // ---- O^T += V^T · P : A=V^T[d][key] from LDS, B=pp; 16 mfma16
        #pragma unroll
        for (int i = 0; i < 4; i++) {
            #pragma unroll
            for (int dt = 0; dt < 4; dt++) {
                const int swz = ((i * 2 + (quad >> 1)) ^ (l15 & 7));
                s16x4 va = *(const s16x4*)&vc_[(dt * 16 + l15) * 64 +
                                               swz * 8 + (quad & 1) * 4];
                acc[dt] = mfma16(va, pp[i], acc[dt]);
            }
        }
    }

    // ---- rsum: lane holds partial for query l15; sum across quads
    rsum += __shfl_xor(rsum, 16, 64);
    rsum += __shfl_xor(rsum, 32, 64);
    const float inv = 1.0f / rsum;

    // ---- epilogue: O^T rows d = dt*16+quad*4+r, col query l15 -> o_t[n][512]
    const int n_glob = nb + l15;
    u16* dst = &o_t[(((bh >> 3) * 3136) + n_glob) * 512 + (bh & 7) * 64];
    #pragma unroll
    for (int dt = 0; dt < 4; dt++) {
        u16x4 o4;
        #pragma unroll
        for (int r = 0; r < 4; r++) o4[r] = f2bf(acc[dt][r] * inv);
        *(u16x4*)&dst[dt * 16 + quad * 4] = o4;
    }
}

// ---------------------------------------------------------------------------
// Output projection MFMA GEMM, no LDS. grid (98 n-tiles of 32, 4 och, 2 b).
// A = wp' [256][512], B = o_t [n][512]; C[och][token] -> fp32 out.
// ---------------------------------------------------------------------------
__global__ __launch_bounds__(256, 4) void proj_kernel(
    const u16* __restrict__ o_t, const u16* __restrict__ wpb,
    const float* __restrict__ bp, float* __restrict__ out)
{
    const int b = blockIdx.z, n0 = blockIdx.x * 32;
    const int och0 = blockIdx.y * 64 + (threadIdx.x >> 6) * 16;
    const int lane = threadIdx.x & 63;
    const int l15 = lane & 15, quad = lane >> 4;
    const f32x4 z = {0.f, 0.f, 0.f, 0.f};

    const u16* arow = &wpb[(och0 + l15) * 512 + quad * 8];
    f32x4 acc[2] = {z, z};
    #pragma unroll 4
    for (int kc = 0; kc < 512; kc += 32) {
        s16x8 a = *(const s16x8*)&arow[kc];
        #pragma unroll
        for (int f = 0; f < 2; f++) {
            s16x8 bf = *(const s16x8*)&o_t[(b * 3136 + n0 + f * 16 + l15) * 512 + kc + quad * 8];
            acc[f] = mfma32(a, bf, acc[f]);
        }
    }
    #pragma unroll
    for (int r = 0; r < 4; r++) {
        const int och = och0 + quad * 4 + r;
        const float bi = bp[och];
        #pragma unroll
        for (int f = 0; f < 2; f++)
            out[(b * 256 + och) * 3136 + n0 + f * 16 + l15] = acc[f][r] + bi;
    }
}

// ---------------------------------------------------------------------------
extern "C" void kernel_launch(void* const* d_in, const int* in_sizes, int n_in,
                              void* d_out, int out_size, void* d_ws, size_t ws_size,
                              hipStream_t stream) {
    const float* x  = (const float*)d_in[0];
    const float* wq = (const float*)d_in[1];
    const float* sq = (const float*)d_in[2];
    const float* bq = (const float*)d_in[3];
    const float* wk = (const float*)d_in[4];
    const float* sk = (const float*)d_in[5];
    const float* bk = (const float*)d_in[6];
    const float* wv = (const float*)d_in[7];
    const float* sv = (const float*)d_in[8];
    const float* bv = (const float*)d_in[9];
    const float* wp = (const float*)d_in[10];
    const float* sp = (const float*)d_in[11];
    const float* bp = (const float*)d_in[12];
    float* out = (float*)d_out;

    u16* qws = (u16*)d_ws;                 // 802816
    u16* kws = qws + 802816;               // 802816
    u16* vws = kws + 802816;               // 3211264
    u16* R   = vws + 3211264;              // 3211264 (x_t then o_t, overlaid)
    u16* xt  = R;
    u16* ot  = R;
    u16* wqb = R + 3211264;                // 32768
    u16* wkb = wqb + 32768;                // 32768
    u16* wvb = wkb + 32768;                // 131072
    u16* wpb = wvb + 131072;               // 131072  (total 16,711,680 B)

    xt_kernel<<<dim3(49, 4, 2), 256, 0, stream>>>(x, xt);
    wconv_kernel<<<dim3(320), 256, 0, stream>>>(wq, sq, wk, sk, wv, sv, wp, sp,
                                                wqb, wkb, wvb, wpb);
    qkv_kernel<<<dim3(49, 12, 2), 256, 0, stream>>>(xt, wqb, wkb, wvb,
                                                    bq, bk, bv, qws, kws, vws);
    attn_kernel<<<dim3(16, 49), 256, 0, stream>>>(qws, kws, vws, ot);
    proj_kernel<<<dim3(98, 4, 2), 256, 0, stream>>>(ot, wpb, bp, out);
}